// Round 6
// baseline (506.374 us; speedup 1.0000x reference)
//
#include <hip/hip_runtime.h>
#include <cstdint>

typedef __attribute__((ext_vector_type(8))) short s8v;   // 8 x bf16 (as i16)
typedef __attribute__((ext_vector_type(4))) float f4v;   // MFMA accumulator

__device__ __forceinline__ unsigned short bf16_rne(float f) {
    unsigned u = __float_as_uint(f);
    u += 0x7FFFu + ((u >> 16) & 1u);
    return (unsigned short)(u >> 16);
}
__device__ __forceinline__ float bf16f(unsigned short h) {
    return __uint_as_float(((unsigned)h) << 16);
}
// two fp32 -> packed bf16-hi dword + packed bf16-lo dword (RNE both)
__device__ __forceinline__ void cvt2(float a, float b, unsigned& hiw, unsigned& low) {
    unsigned ua = __float_as_uint(a), ub = __float_as_uint(b);
    unsigned ha = ua + 0x7FFFu + ((ua >> 16) & 1u);
    unsigned hb = ub + 0x7FFFu + ((ub >> 16) & 1u);
    hiw = (ha >> 16) | (hb & 0xFFFF0000u);
    float ra = a - __uint_as_float(ha & 0xFFFF0000u);
    float rb = b - __uint_as_float(hb & 0xFFFF0000u);
    unsigned la = __float_as_uint(ra), lb = __float_as_uint(rb);
    la += 0x7FFFu + ((la >> 16) & 1u);
    lb += 0x7FFFu + ((lb >> 16) & 1u);
    low = (la >> 16) | (lb & 0xFFFF0000u);
}

// ---------------- transpose x [c][784] -> xt [p][c] fp32 (coalesced both sides) ----------
__global__ __launch_bounds__(256) void transpose_x(const float* __restrict__ x,
                                                   float* __restrict__ xt) {
    __shared__ float t[64][65];
    int c0 = blockIdx.x * 64, p0 = blockIdx.y * 64;
    int l = threadIdx.x & 63, g = threadIdx.x >> 6;
#pragma unroll
    for (int j = 0; j < 16; ++j) {
        int cc = j * 4 + g;
        int p = p0 + l;
        t[cc][l] = (p < 784) ? x[(size_t)(c0 + cc) * 784 + p] : 0.f;
    }
    __syncthreads();
#pragma unroll
    for (int j = 0; j < 16; ++j) {
        int pp = j * 4 + g;
        int p = p0 + pp;
        if (p < 784) xt[(size_t)p * 2048 + c0 + l] = t[l][pp];
    }
}

// ---------------- build im2col B: xt [p][c] fp32 -> Bhi/Blo [p][k=c*9+r] bf16 ------------
__global__ __launch_bounds__(256) void build_B(const float* __restrict__ xt,
                                               unsigned* __restrict__ Bhi,
                                               unsigned* __restrict__ Blo) {
    int p = blockIdx.x;
    int h = p / 28, w = p % 28;
#pragma unroll
    for (int it = 0; it < 4; ++it) {
        int cp = it * 256 + threadIdx.x;   // c-pair index 0..1023, c0 = 2*cp
        float va[18];
#pragma unroll
        for (int r = 0; r < 9; ++r) {
            int h2 = h + r / 3 - 1, w2 = w + r % 3 - 1;
            bool ok = (h2 >= 0) & (h2 < 28) & (w2 >= 0) & (w2 < 28);
            float2 v = ok ? ((const float2*)(xt + (size_t)(h2 * 28 + w2) * 2048))[cp]
                          : float2{0.f, 0.f};
            va[r] = v.x;
            va[9 + r] = v.y;
        }
        size_t base = (size_t)p * 9216 + (size_t)cp * 9;  // dword index
#pragma unroll
        for (int d = 0; d < 9; ++d) {
            unsigned hw, lw;
            cvt2(va[2 * d], va[2 * d + 1], hw, lw);
            Bhi[base + d] = hw;
            Blo[base + d] = lw;
        }
    }
}

// ---------------- conv implicit GEMM; B LDS double-buffered, vmem issued inside MFMA -----
// Per step: [write A(s) to LDS] bar#1(lgkm-only) [issue glds(s+1)->B[!cur] + A-reg loads,
// then ds_read + 42 MFMA] bar#2 (vmcnt drains loads issued ~800cyc earlier -> hidden).
#define AHI_OFF 0
#define ALO_OFF 8192
#define B0_OFF 16384      // BHI at +0, BLO at +7168, per-buffer stride 14336
#define BSTRIDE 14336
#define LDS_BYTES 45056
#define KCH 1536          // 12 * 1536 = 18432
#define NSTEP 48          // KCH / 32

__global__ __launch_bounds__(256, 3) void conv_gemm(const float* __restrict__ cw,
                                                    const char* __restrict__ wsb,
                                                    uint32_t offBhi, uint32_t offBlo,
                                                    float* __restrict__ part) {
    __shared__ char smem[LDS_BYTES];
    int tid = threadIdx.x;
    int lane = tid & 63, wave = tid >> 6;
    int bm0 = blockIdx.x * 128, bn0 = blockIdx.y * 112, z = blockIdx.z;

    // B staging: 14 real glds descriptors (7 hi + 7 lo tiles) + 2 benign dups.
    uint32_t doff[4], dlds[4];
#pragma unroll
    for (int j = 0; j < 4; ++j) {
        int i = j * 4 + wave;           // 0..15
        if (i >= 14) i -= 2;            // dup (same src+dst: benign)
        bool hiP = i < 7;
        int jj = hiP ? i : i - 7;
        int prow = jj * 16 + (lane >> 2);
        int pos = lane & 3;
        int gblk = pos ^ ((prow >> 1) & 3);            // XOR swizzle @16B blocks
        uint32_t elem = (uint32_t)(bn0 + prow) * 18432 + (uint32_t)z * KCH + gblk * 8;
        doff[j] = (hiP ? offBhi : offBlo) + elem * 2;
        dlds[j] = B0_OFF + (hiP ? 0 : 7168) + jj * 1024;
    }

    int m = lane & 15, qd = lane >> 4;
    int sw = (m >> 1) & 3;
    uint32_t apos = (uint32_t)(wave * 32 + m) * 64 + (uint32_t)((qd ^ sw) * 16);
    uint32_t bpos = (uint32_t)m * 64 + (uint32_t)((qd ^ sw) * 16);
    int arow = tid >> 1, ahalf = tid & 1;              // 2 threads per A row
    int swt = (arow >> 1) & 3;                         // writer-row swizzle

    f4v acc[2][7];
#pragma unroll
    for (int a = 0; a < 2; ++a)
#pragma unroll
        for (int b = 0; b < 7; ++b) acc[a][b] = f4v{0.f, 0.f, 0.f, 0.f};

    // A: thread owns half-row (16 fp32/step) of conv_w row bm0+arow.
    const float4* ap = (const float4*)(cw + (size_t)(bm0 + arow) * 18432 + (size_t)z * KCH
                                       + (size_t)ahalf * 16);
    float4 arc[4], arn[4];
#pragma unroll
    for (int j = 0; j < 4; ++j) arc[j] = ap[j];

    // prologue: glds(0) -> buffer 0
#pragma unroll
    for (int j = 0; j < 4; ++j) {
        __builtin_amdgcn_global_load_lds(
            (const __attribute__((address_space(1))) void*)(wsb + doff[j]),
            (__attribute__((address_space(3))) void*)(smem + dlds[j]), 16, 0, 0);
        doff[j] += 64;
    }

    for (int step = 0; step < NSTEP; ++step) {
        // ---- stage: split A(step) fp32 -> bf16 hi/lo, LDS write (no vmem here) ----
        unsigned hw[8], lw[8];
#pragma unroll
        for (int j = 0; j < 4; ++j) {
            cvt2(arc[j].x, arc[j].y, hw[2 * j], lw[2 * j]);
            cvt2(arc[j].z, arc[j].w, hw[2 * j + 1], lw[2 * j + 1]);
        }
#pragma unroll
        for (int b = 0; b < 2; ++b) {
            uint32_t col = (uint32_t)(((2 * ahalf + b) ^ swt) * 16);
            *(uint4*)(smem + AHI_OFF + arow * 64 + col) =
                uint4{hw[4 * b], hw[4 * b + 1], hw[4 * b + 2], hw[4 * b + 3]};
            *(uint4*)(smem + ALO_OFF + arow * 64 + col) =
                uint4{lw[4 * b], lw[4 * b + 1], lw[4 * b + 2], lw[4 * b + 3]};
        }
        __syncthreads();   // bar#1: lgkm-only (vmcnt already drained at prev bar#2)

        // ---- compute section: issue next-step vmem FIRST, then ds_read + MFMA ----
        if (step < NSTEP - 1) {
            uint32_t bofs = (uint32_t)(((step + 1) & 1) * BSTRIDE);
#pragma unroll
            for (int j = 0; j < 4; ++j) {
                __builtin_amdgcn_global_load_lds(
                    (const __attribute__((address_space(1))) void*)(wsb + doff[j]),
                    (__attribute__((address_space(3))) void*)(smem + dlds[j] + bofs), 16, 0, 0);
                doff[j] += 64;
            }
            ap += 8;  // 32 fp32
#pragma unroll
            for (int j = 0; j < 4; ++j) arn[j] = ap[j];
        }

        uint32_t bcur = B0_OFF + (uint32_t)((step & 1) * BSTRIDE);
        s8v ah[2], al[2];
#pragma unroll
        for (int mt = 0; mt < 2; ++mt) {
            ah[mt] = *(const s8v*)(smem + AHI_OFF + apos + mt * 1024);
            al[mt] = *(const s8v*)(smem + ALO_OFF + apos + mt * 1024);
        }
#pragma unroll
        for (int nt = 0; nt < 7; ++nt) {
            s8v bh = *(const s8v*)(smem + bcur + bpos + nt * 1024);
            s8v bl = *(const s8v*)(smem + bcur + 7168 + bpos + nt * 1024);
#pragma unroll
            for (int mt = 0; mt < 2; ++mt) {
                acc[mt][nt] = __builtin_amdgcn_mfma_f32_16x16x32_bf16(ah[mt], bh, acc[mt][nt], 0, 0, 0);
                acc[mt][nt] = __builtin_amdgcn_mfma_f32_16x16x32_bf16(ah[mt], bl, acc[mt][nt], 0, 0, 0);
                acc[mt][nt] = __builtin_amdgcn_mfma_f32_16x16x32_bf16(al[mt], bh, acc[mt][nt], 0, 0, 0);
            }
        }
        __syncthreads();   // bar#2: drains vmem issued a full MFMA-section ago (hidden)

        if (step < NSTEP - 1) {
#pragma unroll
            for (int j = 0; j < 4; ++j) arc[j] = arn[j];
        }
    }

    // epilogue: C row(o) = qd*4+reg, col(p) = m; one 16B store per tile
    float* pz = part + (size_t)z * 1605632;  // 784*2048
#pragma unroll
    for (int mt = 0; mt < 2; ++mt) {
        int o = bm0 + wave * 32 + mt * 16 + qd * 4;
#pragma unroll
        for (int nt = 0; nt < 7; ++nt) {
            int p = bn0 + nt * 16 + m;
            *(float4*)(pz + (size_t)p * 2048 + o) =
                float4{acc[mt][nt].x, acc[mt][nt].y, acc[mt][nt].z, acc[mt][nt].w};
        }
    }
}

// ---------------- heads: block per pixel; 12-partial reduce, 45 dots, sigmoid, scatter ---
__constant__ int HMIN_d[9] = {3, 2, 1, 6, 4, 3, 11, 8, 6};
__constant__ int WMIN_d[9] = {1, 2, 3, 3, 4, 6, 6, 8, 11};

__global__ __launch_bounds__(256) void heads(const float* __restrict__ part,
                                             const float* __restrict__ conv_b,
                                             const float* __restrict__ reg_w,
                                             const float* __restrict__ reg_b,
                                             const float* __restrict__ cls_w,
                                             const float* __restrict__ cls_b,
                                             float* __restrict__ out) {
    int tid = threadIdx.x;
    int lane = tid & 63, wave = tid >> 6;
    int p = blockIdx.x;                 // source pixel p'
    int ci = tid * 2;                   // float4-pair index: channels [tid*8, tid*8+8)

    float4 h0 = ((const float4*)conv_b)[ci];
    float4 h1 = ((const float4*)conv_b)[ci + 1];
#pragma unroll
    for (int z = 0; z < 12; ++z) {
        const float4* pz = (const float4*)(part + (size_t)z * 1605632 + (size_t)p * 2048);
        float4 a = pz[ci], b = pz[ci + 1];
        h0.x += a.x; h0.y += a.y; h0.z += a.z; h0.w += a.w;
        h1.x += b.x; h1.y += b.y; h1.z += b.z; h1.w += b.w;
    }
    h0.x = fmaxf(h0.x, 0.f); h0.y = fmaxf(h0.y, 0.f);
    h0.z = fmaxf(h0.z, 0.f); h0.w = fmaxf(h0.w, 0.f);
    h1.x = fmaxf(h1.x, 0.f); h1.y = fmaxf(h1.y, 0.f);
    h1.z = fmaxf(h1.z, 0.f); h1.w = fmaxf(h1.w, 0.f);

    float s[45];
#pragma unroll
    for (int o = 0; o < 36; ++o) {
        float4 wa = ((const float4*)(reg_w + (size_t)o * 2048))[ci];
        float4 wb = ((const float4*)(reg_w + (size_t)o * 2048))[ci + 1];
        s[o] = h0.x * wa.x + h0.y * wa.y + h0.z * wa.z + h0.w * wa.w +
               h1.x * wb.x + h1.y * wb.y + h1.z * wb.z + h1.w * wb.w;
    }
#pragma unroll
    for (int a = 0; a < 9; ++a) {
        float4 wa = ((const float4*)(cls_w + (size_t)a * 2048))[ci];
        float4 wb = ((const float4*)(cls_w + (size_t)a * 2048))[ci + 1];
        s[36 + a] = h0.x * wa.x + h0.y * wa.y + h0.z * wa.z + h0.w * wa.w +
                    h1.x * wb.x + h1.y * wb.y + h1.z * wb.z + h1.w * wb.w;
    }

    __shared__ float wsum[4][45];
    __shared__ float fin[45];
#pragma unroll
    for (int o = 0; o < 45; ++o) {
        float v = s[o];
#pragma unroll
        for (int d = 1; d < 64; d <<= 1) v += __shfl_xor(v, d, 64);
        if (lane == 0) wsum[wave][o] = v;
    }
    __syncthreads();
    if (tid < 45) fin[tid] = wsum[0][tid] + wsum[1][tid] + wsum[2][tid] + wsum[3][tid];
    __syncthreads();

    // Reference view-chain: valid set over n = pix*9 + a (geometry); data at row n from
    // channel a' = n//784, pixel p' = n%784. This block owns p'; n = a'*784 + p'.
    if (tid < 9) {
        int ap = tid;
        int n = ap * 784 + p;
        int pix = n / 9, a2 = n % 9;
        int hh = pix / 28, ww = pix % 28;
        if (hh >= HMIN_d[a2] && ww >= WMIN_d[a2]) {
            int row = 0;
#pragma unroll
            for (int a3 = 0; a3 < 9; ++a3) {
                int hm = HMIN_d[a3], wm = WMIN_d[a3];
                int full = hh - hm; if (full < 0) full = 0;
                row += full * (28 - wm);
                if (hh >= hm) { int prt = ww - wm; if (prt < 0) prt = 0; row += prt; }
                if (a3 < a2 && hh >= hm && ww >= wm) row += 1;
            }
            float cl = fin[36 + ap] + cls_b[ap];
            float keep = (1.f / (1.f + expf(-cl)) > 0.9f) ? 1.f : 0.f;
#pragma unroll
            for (int q = 0; q < 4; ++q) {
                float rl = fin[q * 9 + ap] + reg_b[q * 9 + ap];
                out[row * 4 + q] = keep / (1.f + expf(-rl));
            }
        }
    }
}

extern "C" void kernel_launch(void* const* d_in, const int* in_sizes, int n_in,
                              void* d_out, int out_size, void* d_ws, size_t ws_size,
                              hipStream_t stream) {
    const float* x = (const float*)d_in[0];
    const float* conv_w = (const float*)d_in[1];
    const float* conv_b = (const float*)d_in[2];
    const float* reg_w = (const float*)d_in[3];
    const float* reg_b = (const float*)d_in[4];
    const float* cls_w = (const float*)d_in[5];
    const float* cls_b = (const float*)d_in[6];
    float* out = (float*)d_out;
    char* ws = (char*)d_ws;

    // workspace layout (bytes) — total 141,295,616 (< proven-safe 164,790,272)
    const size_t o_part = 0;           // fp32 partials [12][784][2048] : 77,070,336
    const size_t o_Bhi = 77070336;     // bf16 [784][18432]             : 28,901,376
    const size_t o_Blo = 105971712;    // bf16 [784][18432]             : 28,901,376
    const size_t o_xt = 134873088;     // fp32 [784][2048]              :  6,422,528

    transpose_x<<<dim3(32, 13), 256, 0, stream>>>(x, (float*)(ws + o_xt));
    build_B<<<784, 256, 0, stream>>>((const float*)(ws + o_xt), (unsigned*)(ws + o_Bhi),
                                     (unsigned*)(ws + o_Blo));
    conv_gemm<<<dim3(16, 7, 12), 256, 0, stream>>>(conv_w, ws, (uint32_t)o_Bhi,
                                                   (uint32_t)o_Blo, (float*)(ws + o_part));
    heads<<<784, 256, 0, stream>>>((const float*)(ws + o_part), conv_b, reg_w, reg_b,
                                   cls_w, cls_b, out);
}

// Round 7
// 487.835 us; speedup vs baseline: 1.0380x; 1.0380x over previous
//
#include <hip/hip_runtime.h>
#include <cstdint>

typedef __attribute__((ext_vector_type(8))) short s8v;   // 8 x bf16 (as i16)
typedef __attribute__((ext_vector_type(4))) float f4v;   // MFMA accumulator

__device__ __forceinline__ unsigned short bf16_rne(float f) {
    unsigned u = __float_as_uint(f);
    u += 0x7FFFu + ((u >> 16) & 1u);
    return (unsigned short)(u >> 16);
}
__device__ __forceinline__ float bf16f(unsigned short h) {
    return __uint_as_float(((unsigned)h) << 16);
}
// RNE pair-split (used in build_B where VALU is not critical)
__device__ __forceinline__ void cvt2(float a, float b, unsigned& hiw, unsigned& low) {
    unsigned ua = __float_as_uint(a), ub = __float_as_uint(b);
    unsigned ha = ua + 0x7FFFu + ((ua >> 16) & 1u);
    unsigned hb = ub + 0x7FFFu + ((ub >> 16) & 1u);
    hiw = (ha >> 16) | (hb & 0xFFFF0000u);
    float ra = a - __uint_as_float(ha & 0xFFFF0000u);
    float rb = b - __uint_as_float(hb & 0xFFFF0000u);
    unsigned la = __float_as_uint(ra), lb = __float_as_uint(rb);
    la += 0x7FFFu + ((la >> 16) & 1u);
    lb += 0x7FFFu + ((lb >> 16) & 1u);
    low = (la >> 16) | (lb & 0xFFFF0000u);
}
// cheap truncation pair-split (conv inner loop): err <= 2^-16 |v|, ~10 VALU/pair
__device__ __forceinline__ void cvt2t(float a, float b, unsigned& hiw, unsigned& low) {
    unsigned ua = __float_as_uint(a), ub = __float_as_uint(b);
    hiw = (ua >> 16) | (ub & 0xFFFF0000u);
    float ra = a - __uint_as_float(ua & 0xFFFF0000u);
    float rb = b - __uint_as_float(ub & 0xFFFF0000u);
    unsigned la = __float_as_uint(ra), lb = __float_as_uint(rb);
    low = (la >> 16) | (lb & 0xFFFF0000u);
}

// ---------------- transpose x [c][784] -> xt [p][c] fp32 (coalesced both sides) ----------
__global__ __launch_bounds__(256) void transpose_x(const float* __restrict__ x,
                                                   float* __restrict__ xt) {
    __shared__ float t[64][65];
    int c0 = blockIdx.x * 64, p0 = blockIdx.y * 64;
    int l = threadIdx.x & 63, g = threadIdx.x >> 6;
#pragma unroll
    for (int j = 0; j < 16; ++j) {
        int cc = j * 4 + g;
        int p = p0 + l;
        t[cc][l] = (p < 784) ? x[(size_t)(c0 + cc) * 784 + p] : 0.f;
    }
    __syncthreads();
#pragma unroll
    for (int j = 0; j < 16; ++j) {
        int pp = j * 4 + g;
        int p = p0 + pp;
        if (p < 784) xt[(size_t)p * 2048 + c0 + l] = t[l][pp];
    }
}

// ---------------- build im2col B: xt [p][c] fp32 -> Bhi/Blo [p][k=c*9+r] bf16 ------------
__global__ __launch_bounds__(256) void build_B(const float* __restrict__ xt,
                                               unsigned* __restrict__ Bhi,
                                               unsigned* __restrict__ Blo) {
    int p = blockIdx.x;
    int h = p / 28, w = p % 28;
#pragma unroll
    for (int it = 0; it < 4; ++it) {
        int cp = it * 256 + threadIdx.x;   // c-pair index 0..1023, c0 = 2*cp
        float va[18];
#pragma unroll
        for (int r = 0; r < 9; ++r) {
            int h2 = h + r / 3 - 1, w2 = w + r % 3 - 1;
            bool ok = (h2 >= 0) & (h2 < 28) & (w2 >= 0) & (w2 < 28);
            float2 v = ok ? ((const float2*)(xt + (size_t)(h2 * 28 + w2) * 2048))[cp]
                          : float2{0.f, 0.f};
            va[r] = v.x;
            va[9 + r] = v.y;
        }
        size_t base = (size_t)p * 9216 + (size_t)cp * 9;  // dword index
#pragma unroll
        for (int d = 0; d < 9; ++d) {
            unsigned hw, lw;
            cvt2(va[2 * d], va[2 * d + 1], hw, lw);
            Bhi[base + d] = hw;
            Blo[base + d] = lw;
        }
    }
}

// ---------------- conv implicit GEMM over k=c*9+r; z=16 K-split; trunc split; occ=4 ------
#define AHI_OFF 0
#define ALO_OFF 8192
#define BHI_OFF 16384
#define BLO_OFF 23552
#define LDS_BYTES 30720
#define KCH 1152          // 16 * 1152 = 18432
#define NSTEP 36          // KCH / 32

__global__ __launch_bounds__(256, 4) void conv_gemm(const float* __restrict__ cw,
                                                    const char* __restrict__ wsb,
                                                    uint32_t offBhi, uint32_t offBlo,
                                                    float* __restrict__ part) {
    __shared__ char smem[LDS_BYTES];
    int tid = threadIdx.x;
    int lane = tid & 63, wave = tid >> 6;
    int bm0 = blockIdx.x * 128, bn0 = blockIdx.y * 112, z = blockIdx.z;

    // B staging: 14 real glds descriptors (7 hi + 7 lo tiles) + 2 benign dups.
    uint32_t doff[4], dlds[4];
#pragma unroll
    for (int j = 0; j < 4; ++j) {
        int i = j * 4 + wave;           // 0..15
        if (i >= 14) i -= 2;            // dup (same src+dst: benign)
        bool hiP = i < 7;
        int jj = hiP ? i : i - 7;
        int prow = jj * 16 + (lane >> 2);
        int pos = lane & 3;
        int gblk = pos ^ ((prow >> 1) & 3);            // XOR swizzle @16B blocks
        uint32_t elem = (uint32_t)(bn0 + prow) * 18432 + (uint32_t)z * KCH + gblk * 8;
        doff[j] = (hiP ? offBhi : offBlo) + elem * 2;
        dlds[j] = (hiP ? BHI_OFF : BLO_OFF) + jj * 1024;
    }

    int m = lane & 15, qd = lane >> 4;
    int sw = (m >> 1) & 3;
    uint32_t apos = (uint32_t)(wave * 32 + m) * 64 + (uint32_t)((qd ^ sw) * 16);
    uint32_t bpos = (uint32_t)m * 64 + (uint32_t)((qd ^ sw) * 16);
    int arow = tid >> 1, ahalf = tid & 1;              // 2 threads per A row
    int swt = (arow >> 1) & 3;                         // writer-row swizzle

    f4v acc[2][7];
#pragma unroll
    for (int a = 0; a < 2; ++a)
#pragma unroll
        for (int b = 0; b < 7; ++b) acc[a][b] = f4v{0.f, 0.f, 0.f, 0.f};

    // A: thread owns half-row (16 fp32/step) of conv_w row bm0+arow. Double-buffered regs.
    const float4* ap = (const float4*)(cw + (size_t)(bm0 + arow) * 18432 + (size_t)z * KCH
                                       + (size_t)ahalf * 16);
    float4 arc[4], arn[4];
#pragma unroll
    for (int j = 0; j < 4; ++j) arc[j] = ap[j];

    for (int step = 0; step < NSTEP; ++step) {
        // B: async global->LDS
#pragma unroll
        for (int j = 0; j < 4; ++j) {
            __builtin_amdgcn_global_load_lds(
                (const __attribute__((address_space(1))) void*)(wsb + doff[j]),
                (__attribute__((address_space(3))) void*)(smem + dlds[j]), 16, 0, 0);
            doff[j] += 64;  // 32 k * 2B
        }
        // A: prefetch next step
        if (step < NSTEP - 1) {
            ap += 8;  // 32 fp32
#pragma unroll
            for (int j = 0; j < 4; ++j) arn[j] = ap[j];
        }
        // split current A fp32 -> bf16 hi/lo (truncation), LDS write (swizzled 16B blocks)
        unsigned hw[8], lw[8];
#pragma unroll
        for (int j = 0; j < 4; ++j) {
            cvt2t(arc[j].x, arc[j].y, hw[2 * j], lw[2 * j]);
            cvt2t(arc[j].z, arc[j].w, hw[2 * j + 1], lw[2 * j + 1]);
        }
#pragma unroll
        for (int b = 0; b < 2; ++b) {
            uint32_t col = (uint32_t)(((2 * ahalf + b) ^ swt) * 16);
            *(uint4*)(smem + AHI_OFF + arow * 64 + col) =
                uint4{hw[4 * b], hw[4 * b + 1], hw[4 * b + 2], hw[4 * b + 3]};
            *(uint4*)(smem + ALO_OFF + arow * 64 + col) =
                uint4{lw[4 * b], lw[4 * b + 1], lw[4 * b + 2], lw[4 * b + 3]};
        }
        __syncthreads();

        s8v ah[2], al[2];
#pragma unroll
        for (int mt = 0; mt < 2; ++mt) {
            ah[mt] = *(const s8v*)(smem + AHI_OFF + apos + mt * 1024);
            al[mt] = *(const s8v*)(smem + ALO_OFF + apos + mt * 1024);
        }
#pragma unroll
        for (int nt = 0; nt < 7; ++nt) {
            s8v bh = *(const s8v*)(smem + BHI_OFF + bpos + nt * 1024);
            s8v bl = *(const s8v*)(smem + BLO_OFF + bpos + nt * 1024);
#pragma unroll
            for (int mt = 0; mt < 2; ++mt) {
                acc[mt][nt] = __builtin_amdgcn_mfma_f32_16x16x32_bf16(ah[mt], bh, acc[mt][nt], 0, 0, 0);
                acc[mt][nt] = __builtin_amdgcn_mfma_f32_16x16x32_bf16(ah[mt], bl, acc[mt][nt], 0, 0, 0);
                acc[mt][nt] = __builtin_amdgcn_mfma_f32_16x16x32_bf16(al[mt], bh, acc[mt][nt], 0, 0, 0);
            }
        }
        __syncthreads();

        if (step < NSTEP - 1) {
#pragma unroll
            for (int j = 0; j < 4; ++j) arc[j] = arn[j];
        }
    }

    // epilogue: C row(o) = qd*4+reg, col(p) = m; one 16B store per tile
    float* pz = part + (size_t)z * 1605632;  // 784*2048
#pragma unroll
    for (int mt = 0; mt < 2; ++mt) {
        int o = bm0 + wave * 32 + mt * 16 + qd * 4;
#pragma unroll
        for (int nt = 0; nt < 7; ++nt) {
            int p = bn0 + nt * 16 + m;
            *(float4*)(pz + (size_t)p * 2048 + o) =
                float4{acc[mt][nt].x, acc[mt][nt].y, acc[mt][nt].z, acc[mt][nt].w};
        }
    }
}

// ---------------- heads: block per pixel; 16-partial reduce, 45 dots, sigmoid, scatter ---
__constant__ int HMIN_d[9] = {3, 2, 1, 6, 4, 3, 11, 8, 6};
__constant__ int WMIN_d[9] = {1, 2, 3, 3, 4, 6, 6, 8, 11};

__global__ __launch_bounds__(256) void heads(const float* __restrict__ part,
                                             const float* __restrict__ conv_b,
                                             const float* __restrict__ reg_w,
                                             const float* __restrict__ reg_b,
                                             const float* __restrict__ cls_w,
                                             const float* __restrict__ cls_b,
                                             float* __restrict__ out) {
    int tid = threadIdx.x;
    int lane = tid & 63, wave = tid >> 6;
    int p = blockIdx.x;                 // source pixel p'
    int ci = tid * 2;                   // float4-pair index: channels [tid*8, tid*8+8)

    float4 h0 = ((const float4*)conv_b)[ci];
    float4 h1 = ((const float4*)conv_b)[ci + 1];
#pragma unroll
    for (int z = 0; z < 16; ++z) {
        const float4* pz = (const float4*)(part + (size_t)z * 1605632 + (size_t)p * 2048);
        float4 a = pz[ci], b = pz[ci + 1];
        h0.x += a.x; h0.y += a.y; h0.z += a.z; h0.w += a.w;
        h1.x += b.x; h1.y += b.y; h1.z += b.z; h1.w += b.w;
    }
    h0.x = fmaxf(h0.x, 0.f); h0.y = fmaxf(h0.y, 0.f);
    h0.z = fmaxf(h0.z, 0.f); h0.w = fmaxf(h0.w, 0.f);
    h1.x = fmaxf(h1.x, 0.f); h1.y = fmaxf(h1.y, 0.f);
    h1.z = fmaxf(h1.z, 0.f); h1.w = fmaxf(h1.w, 0.f);

    float s[45];
#pragma unroll
    for (int o = 0; o < 36; ++o) {
        float4 wa = ((const float4*)(reg_w + (size_t)o * 2048))[ci];
        float4 wb = ((const float4*)(reg_w + (size_t)o * 2048))[ci + 1];
        s[o] = h0.x * wa.x + h0.y * wa.y + h0.z * wa.z + h0.w * wa.w +
               h1.x * wb.x + h1.y * wb.y + h1.z * wb.z + h1.w * wb.w;
    }
#pragma unroll
    for (int a = 0; a < 9; ++a) {
        float4 wa = ((const float4*)(cls_w + (size_t)a * 2048))[ci];
        float4 wb = ((const float4*)(cls_w + (size_t)a * 2048))[ci + 1];
        s[36 + a] = h0.x * wa.x + h0.y * wa.y + h0.z * wa.z + h0.w * wa.w +
                    h1.x * wb.x + h1.y * wb.y + h1.z * wb.z + h1.w * wb.w;
    }

    __shared__ float wsum[4][45];
    __shared__ float fin[45];
#pragma unroll
    for (int o = 0; o < 45; ++o) {
        float v = s[o];
#pragma unroll
        for (int d = 1; d < 64; d <<= 1) v += __shfl_xor(v, d, 64);
        if (lane == 0) wsum[wave][o] = v;
    }
    __syncthreads();
    if (tid < 45) fin[tid] = wsum[0][tid] + wsum[1][tid] + wsum[2][tid] + wsum[3][tid];
    __syncthreads();

    // Reference view-chain: valid set over n = pix*9 + a (geometry); data at row n from
    // channel a' = n//784, pixel p' = n%784. This block owns p'; n = a'*784 + p'.
    if (tid < 9) {
        int ap = tid;
        int n = ap * 784 + p;
        int pix = n / 9, a2 = n % 9;
        int hh = pix / 28, ww = pix % 28;
        if (hh >= HMIN_d[a2] && ww >= WMIN_d[a2]) {
            int row = 0;
#pragma unroll
            for (int a3 = 0; a3 < 9; ++a3) {
                int hm = HMIN_d[a3], wm = WMIN_d[a3];
                int full = hh - hm; if (full < 0) full = 0;
                row += full * (28 - wm);
                if (hh >= hm) { int prt = ww - wm; if (prt < 0) prt = 0; row += prt; }
                if (a3 < a2 && hh >= hm && ww >= wm) row += 1;
            }
            float cl = fin[36 + ap] + cls_b[ap];
            float keep = (1.f / (1.f + expf(-cl)) > 0.9f) ? 1.f : 0.f;
#pragma unroll
            for (int q = 0; q < 4; ++q) {
                float rl = fin[q * 9 + ap] + reg_b[q * 9 + ap];
                out[row * 4 + q] = keep / (1.f + expf(-rl));
            }
        }
    }
}

extern "C" void kernel_launch(void* const* d_in, const int* in_sizes, int n_in,
                              void* d_out, int out_size, void* d_ws, size_t ws_size,
                              hipStream_t stream) {
    const float* x = (const float*)d_in[0];
    const float* conv_w = (const float*)d_in[1];
    const float* conv_b = (const float*)d_in[2];
    const float* reg_w = (const float*)d_in[3];
    const float* reg_b = (const float*)d_in[4];
    const float* cls_w = (const float*)d_in[5];
    const float* cls_b = (const float*)d_in[6];
    float* out = (float*)d_out;
    char* ws = (char*)d_ws;

    // workspace layout (bytes) — total 160,563,200 (== r3's proven-safe size)
    // xt (6.4 MB) is ALIASED onto part[z=0]: xt is fully consumed by build_B before
    // conv_gemm runs (same-stream ordering), so the overlap is safe.
    const size_t o_part = 0;           // fp32 partials [16][784][2048] : 102,760,448
    const size_t o_xt = 0;             // fp32 [784][2048] (aliased, dead before conv)
    const size_t o_Bhi = 102760448;    // bf16 [784][18432]             : 28,901,376
    const size_t o_Blo = 131661824;    // bf16 [784][18432]             : 28,901,376

    transpose_x<<<dim3(32, 13), 256, 0, stream>>>(x, (float*)(ws + o_xt));
    build_B<<<784, 256, 0, stream>>>((const float*)(ws + o_xt), (unsigned*)(ws + o_Bhi),
                                     (unsigned*)(ws + o_Blo));
    conv_gemm<<<dim3(16, 7, 16), 256, 0, stream>>>(conv_w, ws, (uint32_t)o_Bhi,
                                                   (uint32_t)o_Blo, (float*)(ws + o_part));
    heads<<<784, 256, 0, stream>>>((const float*)(ws + o_part), conv_b, reg_w, reg_b,
                                   cls_w, cls_b, out);
}